// Round 1
// baseline (3918.514 us; speedup 1.0000x reference)
//
#include <hip/hip_runtime.h>
#include <hip/hip_bf16.h>
#include <stdint.h>
#include <stddef.h>

#define Bb 16
#define Nn 512
#define Ee 6144
#define Dd 256
#define ROWS (Bb * Ee)   // 98304

typedef short bf16x8 __attribute__((ext_vector_type(8)));
typedef float f32x4 __attribute__((ext_vector_type(4)));

__device__ __forceinline__ unsigned short f2bf(float f) {
  union { float f; unsigned u; } v; v.f = f;
  return (unsigned short)((v.u + 0x7fffu + ((v.u >> 16) & 1u)) >> 16);
}

// ---------------- weight transpose: f32 [K][N] -> bf16 [N][K], batched over z ----------------
__global__ void transpose_w(const float* __restrict__ in, unsigned short* __restrict__ out,
                            int K, int Ncol) {
  __shared__ float tile[32][33];
  const float* inb = in + (size_t)blockIdx.z * K * Ncol;
  unsigned short* outb = out + (size_t)blockIdx.z * K * Ncol;
  int bk = blockIdx.x * 32, bn = blockIdx.y * 32;
  int tx = threadIdx.x, ty = threadIdx.y;
#pragma unroll
  for (int i = 0; i < 32; i += 8)
    tile[ty + i][tx] = inb[(size_t)(bk + ty + i) * Ncol + (bn + tx)];
  __syncthreads();
#pragma unroll
  for (int i = 0; i < 32; i += 8)
    outb[(size_t)(bn + ty + i) * K + (bk + tx)] = f2bf(tile[tx][ty + i]);
}

// ---------------- atom_state init: gather embedding rows ----------------
__global__ void atom_init(const int* __restrict__ cls, const float* __restrict__ emb,
                          float* __restrict__ atom) {
  int site = blockIdx.x, d = threadIdx.x;
  atom[(size_t)site * Dd + d] = emb[(size_t)cls[site] * Dd + d];
}

// ---------------- generic MFMA GEMM ----------------
struct GP {
  const unsigned short* Wt;   // [NC][K] bf16 (pre-transposed weights)
  const float* bias;          // [NC]
  const float* bond;          // [ROWS][D] f32
  const float* atom;          // [B*N][D] f32
  const unsigned short* h1;   // [ROWS][512] bf16
  const int* conn;            // [ROWS][2]
  const float* dist;          // [ROWS]
  const float* centers;       // [128]
  const float* gapP;          // [1]
  unsigned short* outH1;      // [ROWS][512] bf16
  float* outBond;             // [ROWS][D]
  float* outDelta;            // [B*N][D]
};

#define A_EDGE1 0
#define A_NODE1 1
#define A_H1    2
#define A_RBF   3
#define EP_H1RELU 0
#define EP_EDGE2  1
#define EP_NODE2  2
#define EP_BOND0  3

template <int K, int NC, int AL, int EP>
__global__ __launch_bounds__(256, 2) void gemm_k(GP p) {
  __shared__ __align__(16) unsigned short lA[128 * 64];
  __shared__ __align__(16) unsigned short lB[128 * 64];
  const int t = threadIdx.x;
  const int bm = blockIdx.x * 128, bn = blockIdx.y * 128;
  const int srow = t & 127;          // staged row within tile
  const int skc = (t >> 7) * 32;     // 32 cols per thread, 2 threads/row
  const int m = bm + srow;

  const float* pS0 = nullptr;
  const float* pS1 = nullptr;
  const float* pS2 = nullptr;
  float dval = 0.f, gapv = 0.f;
  if (AL == A_EDGE1) {
    int b = m / Ee;
    int i0 = p.conn[2 * m], i1 = p.conn[2 * m + 1];
    pS0 = p.bond + (size_t)m * Dd;
    pS1 = p.atom + ((size_t)b * Nn + i1) * Dd;
    pS2 = p.atom + ((size_t)b * Nn + i0) * Dd;
  } else if (AL == A_NODE1) {
    int b = m / Ee;
    int i1 = p.conn[2 * m + 1];
    pS0 = p.atom + ((size_t)b * Nn + i1) * Dd;
    pS1 = p.bond + (size_t)m * Dd;
  } else if (AL == A_RBF) {
    dval = p.dist[m];
    if (dval == 0.f) dval = 1.f;
    gapv = *p.gapP;
  }
  const unsigned short* pH1 = (AL == A_H1) ? (p.h1 + (size_t)m * K + skc) : nullptr;
  const unsigned short* pBt = p.Wt + (size_t)(bn + srow) * K + skc;

  const int wid = t >> 6, lane = t & 63;
  const int wm = (wid & 1) * 64, wn = (wid >> 1) * 64;
  const int fr = lane & 15, fk0 = (lane >> 4) * 8;

  f32x4 acc[4][4] = {};

  for (int k0 = 0; k0 < K; k0 += 64) {
    // ---- fetch A segment (32 bf16/thread) into regs ----
    union __align__(16) { unsigned short us[32]; bf16x8 v[4]; } ab;
    if (AL == A_H1) {
      const bf16x8* s = (const bf16x8*)(pH1 + k0);
#pragma unroll
      for (int c = 0; c < 4; c++) ab.v[c] = s[c];
    } else if (AL == A_RBF) {
#pragma unroll
      for (int j = 0; j < 32; j++) {
        float x = dval - p.centers[k0 + skc + j];
        ab.us[j] = f2bf(__expf(-gapv * x * x));
      }
    } else {
      int kg = k0 + skc;
      const float* src;
      if (AL == A_EDGE1) src = (kg < 256) ? pS0 : ((kg < 512) ? pS1 : pS2);
      else               src = (kg < 256) ? pS0 : pS1;
      const f32x4* f4 = (const f32x4*)(src + (kg & 255));
#pragma unroll
      for (int c = 0; c < 8; c++) {
        f32x4 v = f4[c];
        ab.us[4 * c + 0] = f2bf(v.x);
        ab.us[4 * c + 1] = f2bf(v.y);
        ab.us[4 * c + 2] = f2bf(v.z);
        ab.us[4 * c + 3] = f2bf(v.w);
      }
    }
    // ---- fetch B segment (32 bf16/thread) ----
    union __align__(16) { unsigned short us[32]; bf16x8 v[4]; } bb;
    {
      const bf16x8* s = (const bf16x8*)(pBt + k0);
#pragma unroll
      for (int c = 0; c < 4; c++) bb.v[c] = s[c];
    }
    __syncthreads();  // previous iteration's LDS reads complete
#pragma unroll
    for (int c = 0; c < 4; c++) {
      int byteo = (skc + c * 8) * 2;
      int swz = byteo ^ ((srow & 7) << 4);
      *(bf16x8*)((char*)lA + srow * 128 + swz) = ab.v[c];
      *(bf16x8*)((char*)lB + srow * 128 + swz) = bb.v[c];
    }
    __syncthreads();
    // ---- MFMA over BK=64 (two K=32 steps) ----
#pragma unroll
    for (int kk = 0; kk < 64; kk += 32) {
      bf16x8 af[4], bfq[4];
#pragma unroll
      for (int f = 0; f < 4; f++) {
        int r = wm + f * 16 + fr;
        af[f] = *(const bf16x8*)((const char*)lA + r * 128 +
                                 (((kk + fk0) * 2) ^ ((r & 7) << 4)));
        int cq = wn + f * 16 + fr;
        bfq[f] = *(const bf16x8*)((const char*)lB + cq * 128 +
                                  (((kk + fk0) * 2) ^ ((cq & 7) << 4)));
      }
#pragma unroll
      for (int i = 0; i < 4; i++)
#pragma unroll
        for (int j = 0; j < 4; j++)
          acc[i][j] = __builtin_amdgcn_mfma_f32_16x16x32_bf16(af[i], bfq[j], acc[i][j], 0, 0, 0);
    }
  }

  // ---- epilogue ----
#pragma unroll
  for (int i = 0; i < 4; i++) {
#pragma unroll
    for (int j = 0; j < 4; j++) {
      int gcol = bn + wn + j * 16 + fr;
      float bv = p.bias[gcol];
#pragma unroll
      for (int v = 0; v < 4; v++) {
        int grow = bm + wm + i * 16 + (lane >> 4) * 4 + v;
        float val = acc[i][j][v] + bv;
        if (EP == EP_H1RELU) {
          p.outH1[(size_t)grow * NC + gcol] = f2bf(fmaxf(val, 0.f));
        } else if (EP == EP_BOND0) {
          p.outBond[(size_t)grow * Dd + gcol] = val;
        } else if (EP == EP_EDGE2) {
          if (p.dist[grow] != 0.f) p.outBond[(size_t)grow * Dd + gcol] += val;
        } else {  // EP_NODE2: scatter-add onto target node
          int b = grow / Ee;
          int n0i = p.conn[2 * grow];
          atomicAdd(p.outDelta + ((size_t)b * Nn + n0i) * Dd + gcol, val);
        }
      }
    }
  }
}

// ---------------- apply node delta with atom mask ----------------
__global__ void apply_delta(float* __restrict__ atom, const float* __restrict__ delta,
                            const int* __restrict__ cls) {
  int site = blockIdx.x, d = threadIdx.x;
  if (cls[site] != 0) atom[(size_t)site * Dd + d] += delta[(size_t)site * Dd + d];
}

// ---------------- final readout: offset MLP + masked mean pool ----------------
__global__ void pool_k(const float* __restrict__ atom, const int* __restrict__ cls,
                       const float* __restrict__ meanEmb, const float* __restrict__ oW,
                       const float* __restrict__ ob, float* __restrict__ out) {
  __shared__ float w[Dd];
  __shared__ float red[256];
  __shared__ float redc[256];
  int b = blockIdx.x, t = threadIdx.x;
  w[t] = oW[t];
  __syncthreads();
  float sum = 0.f, cnt = 0.f;
  for (int n = t; n < Nn; n += 256) {
    int site = b * Nn + n;
    int c = cls[site];
    const float* a = atom + (size_t)site * Dd;
    float dot = 0.f;
    for (int d = 0; d < Dd; d++) dot += a[d] * w[d];
    if (c != 0) { sum += meanEmb[c] + dot + ob[0]; cnt += 1.f; }
  }
  red[t] = sum; redc[t] = cnt;
  __syncthreads();
  for (int s = 128; s > 0; s >>= 1) {
    if (t < s) { red[t] += red[t + s]; redc[t] += redc[t + s]; }
    __syncthreads();
  }
  if (t == 0) out[b] = red[0] / redc[0];
}

extern "C" void kernel_launch(void* const* d_in, const int* in_sizes, int n_in,
                              void* d_out, int out_size, void* d_ws, size_t ws_size,
                              hipStream_t stream) {
  const int* site_class = (const int*)d_in[0];
  const float* distance = (const float*)d_in[1];
  const int* conn       = (const int*)d_in[2];
  const float* atom_emb = (const float*)d_in[3];
  const float* mean_emb = (const float*)d_in[4];
  const float* centers  = (const float*)d_in[5];
  const float* gapP     = (const float*)d_in[6];
  const float* bond_W   = (const float*)d_in[7];
  const float* bond_b   = (const float*)d_in[8];
  const float* offset_W = (const float*)d_in[9];
  const float* offset_b = (const float*)d_in[10];
  const float* edge_W1  = (const float*)d_in[11];
  const float* edge_b1  = (const float*)d_in[12];
  const float* edge_W2  = (const float*)d_in[13];
  const float* edge_b2  = (const float*)d_in[14];
  const float* node_W1  = (const float*)d_in[15];
  const float* node_b1  = (const float*)d_in[16];
  const float* node_W2  = (const float*)d_in[17];
  const float* node_b2  = (const float*)d_in[18];

  char* ws = (char*)d_ws;
  float* atom  = (float*)(ws + 0);                     //  8,388,608 B
  float* delta = (float*)(ws + 8388608);               //  8,388,608 B
  float* bond  = (float*)(ws + 16777216);              // 100,663,296 B
  unsigned short* h1   = (unsigned short*)(ws + 117440512);  // 100,663,296 B
  unsigned short* bWT  = (unsigned short*)(ws + 218103808);  //    65,536 B
  unsigned short* eW1T = (unsigned short*)(ws + 218169344);  // 4,718,592 B
  unsigned short* eW2T = (unsigned short*)(ws + 222887936);  // 1,572,864 B
  unsigned short* nW1T = (unsigned short*)(ws + 224460800);  // 3,145,728 B
  unsigned short* nW2T = (unsigned short*)(ws + 227606528);  // 1,572,864 B

  dim3 tb(32, 8);
  transpose_w<<<dim3(4, 8, 1), tb, 0, stream>>>(bond_W, bWT, 128, 256);
  transpose_w<<<dim3(24, 16, 6), tb, 0, stream>>>(edge_W1, eW1T, 768, 512);
  transpose_w<<<dim3(16, 8, 6), tb, 0, stream>>>(edge_W2, eW2T, 512, 256);
  transpose_w<<<dim3(16, 16, 6), tb, 0, stream>>>(node_W1, nW1T, 512, 512);
  transpose_w<<<dim3(16, 8, 6), tb, 0, stream>>>(node_W2, nW2T, 512, 256);

  atom_init<<<Bb * Nn, 256, 0, stream>>>(site_class, atom_emb, atom);

  GP p{};
  p.conn = conn; p.dist = distance; p.centers = centers; p.gapP = gapP;
  p.bond = bond; p.atom = atom; p.h1 = h1;
  p.outBond = bond; p.outDelta = delta; p.outH1 = h1;

  {  // bond_state = rbf @ bond_W + bond_b
    GP q = p; q.Wt = bWT; q.bias = bond_b;
    gemm_k<128, 256, A_RBF, EP_BOND0><<<dim3(768, 2), 256, 0, stream>>>(q);
  }

  for (int i = 0; i < 6; i++) {
    {  // edge MLP layer 1: [bond|src|tgt] @ W1 -> relu -> h1
      GP q = p; q.Wt = eW1T + (size_t)i * 512 * 768; q.bias = edge_b1 + i * 512;
      gemm_k<768, 512, A_EDGE1, EP_H1RELU><<<dim3(768, 4), 256, 0, stream>>>(q);
    }
    {  // edge MLP layer 2: h1 @ W2 -> bond += mask * (.)
      GP q = p; q.Wt = eW2T + (size_t)i * 256 * 512; q.bias = edge_b2 + i * 256;
      gemm_k<512, 256, A_H1, EP_EDGE2><<<dim3(768, 2), 256, 0, stream>>>(q);
    }
    {  // node MLP layer 1: [src|bond] @ W1 -> relu -> h1
      GP q = p; q.Wt = nW1T + (size_t)i * 512 * 512; q.bias = node_b1 + i * 512;
      gemm_k<512, 512, A_NODE1, EP_H1RELU><<<dim3(768, 4), 256, 0, stream>>>(q);
    }
    hipMemsetAsync(delta, 0, (size_t)Bb * Nn * Dd * 4, stream);
    {  // node MLP layer 2 + scatter-add to delta
      GP q = p; q.Wt = nW2T + (size_t)i * 256 * 512; q.bias = node_b2 + i * 256;
      gemm_k<512, 256, A_H1, EP_NODE2><<<dim3(768, 2), 256, 0, stream>>>(q);
    }
    apply_delta<<<Bb * Nn, 256, 0, stream>>>(atom, delta, site_class);
  }

  pool_k<<<Bb, 256, 0, stream>>>(atom, site_class, mean_emb, offset_W, offset_b, (float*)d_out);
}

// Round 2
// 2367.692 us; speedup vs baseline: 1.6550x; 1.6550x over previous
//
#include <hip/hip_runtime.h>
#include <hip/hip_bf16.h>
#include <stdint.h>
#include <stddef.h>

#define Bb 16
#define Nn 512
#define Ee 6144
#define Dd 256
#define ROWS (Bb * Ee)   // 98304
#define HALF (ROWS / 2)  // 49152

typedef short bf16x8 __attribute__((ext_vector_type(8)));
typedef float f32x4 __attribute__((ext_vector_type(4)));

__device__ __forceinline__ unsigned short f2bf(float f) {
  union { float f; unsigned u; } v; v.f = f;
  return (unsigned short)((v.u + 0x7fffu + ((v.u >> 16) & 1u)) >> 16);
}

__device__ __forceinline__ void gload16(const void* g, void* l) {
  __builtin_amdgcn_global_load_lds(
      (const __attribute__((address_space(1))) void*)g,
      (__attribute__((address_space(3))) void*)l, 16, 0, 0);
}

// ---------------- weight transpose: f32 [K][N] -> bf16 [N][K], batched over z ----------------
__global__ void transpose_w(const float* __restrict__ in, unsigned short* __restrict__ out,
                            int K, int Ncol) {
  __shared__ float tile[32][33];
  const float* inb = in + (size_t)blockIdx.z * K * Ncol;
  unsigned short* outb = out + (size_t)blockIdx.z * K * Ncol;
  int bk = blockIdx.x * 32, bn = blockIdx.y * 32;
  int tx = threadIdx.x, ty = threadIdx.y;
#pragma unroll
  for (int i = 0; i < 32; i += 8)
    tile[ty + i][tx] = inb[(size_t)(bk + ty + i) * Ncol + (bn + tx)];
  __syncthreads();
#pragma unroll
  for (int i = 0; i < 32; i += 8)
    outb[(size_t)(bn + ty + i) * K + (bk + tx)] = f2bf(tile[tx][ty + i]);
}

// ---------------- atom_state init ----------------
__global__ void atom_init(const int* __restrict__ cls, const float* __restrict__ emb,
                          float* __restrict__ atom, unsigned short* __restrict__ atomBf) {
  int s_ = blockIdx.x, d = threadIdx.x;
  size_t o = (size_t)s_ * Dd + d;
  float v = emb[(size_t)cls[s_] * Dd + d];
  atom[o] = v;
  atomBf[o] = f2bf(v);
}

// ---------------- after node scatter: re-impose mask, refresh bf16 mirror ----------------
__global__ void atom_fix(const int* __restrict__ cls, const float* __restrict__ emb,
                         float* __restrict__ atom, unsigned short* __restrict__ atomBf) {
  int s_ = blockIdx.x, d = threadIdx.x;
  size_t o = (size_t)s_ * Dd + d;
  float v = (cls[s_] == 0) ? emb[d] : atom[o];
  atom[o] = v;
  atomBf[o] = f2bf(v);
}

// ---------------- RBF gemm: bond_state = rbf(dist) @ bond_W + b (128^2 tile) ----------------
__global__ __launch_bounds__(256, 2) void gemm_rbf(
    const unsigned short* __restrict__ Wt, const float* __restrict__ bias,
    const float* __restrict__ dist, const float* __restrict__ centers,
    const float* __restrict__ gapP, float* __restrict__ bond,
    unsigned short* __restrict__ bondBf) {
  __shared__ __align__(16) unsigned short lA[128 * 64];
  __shared__ __align__(16) unsigned short lB[128 * 64];
  const int t = threadIdx.x;
  const int bm = blockIdx.x * 128, bn = blockIdx.y * 128;
  const int srow = t & 127, skc = (t >> 7) * 32;
  const int m = bm + srow;
  float dval = dist[m]; if (dval == 0.f) dval = 1.f;
  float gapv = *gapP;
  const unsigned short* pBt = Wt + (size_t)(bn + srow) * 128 + skc;
  const int wid = t >> 6, lane = t & 63;
  const int wm = (wid & 1) * 64, wn = (wid >> 1) * 64;
  const int fr = lane & 15, fk0 = (lane >> 4) * 8;
  f32x4 acc[4][4] = {};
  for (int k0 = 0; k0 < 128; k0 += 64) {
    union __align__(16) { unsigned short us[32]; bf16x8 v[4]; } ab, bb;
#pragma unroll
    for (int j = 0; j < 32; j++) {
      float x = dval - centers[k0 + skc + j];
      ab.us[j] = f2bf(__expf(-gapv * x * x));
    }
    const bf16x8* s = (const bf16x8*)(pBt + k0);
#pragma unroll
    for (int c = 0; c < 4; c++) bb.v[c] = s[c];
    __syncthreads();
#pragma unroll
    for (int c = 0; c < 4; c++) {
      int byteo = (skc + c * 8) * 2;
      int swz = byteo ^ ((srow & 7) << 4);
      *(bf16x8*)((char*)lA + srow * 128 + swz) = ab.v[c];
      *(bf16x8*)((char*)lB + srow * 128 + swz) = bb.v[c];
    }
    __syncthreads();
#pragma unroll
    for (int kk = 0; kk < 64; kk += 32) {
      bf16x8 af[4], bfq[4];
#pragma unroll
      for (int f = 0; f < 4; f++) {
        int r = wm + f * 16 + fr;
        af[f] = *(const bf16x8*)((const char*)lA + r * 128 + (((kk + fk0) * 2) ^ ((r & 7) << 4)));
        int cq = wn + f * 16 + fr;
        bfq[f] = *(const bf16x8*)((const char*)lB + cq * 128 + (((kk + fk0) * 2) ^ ((cq & 7) << 4)));
      }
#pragma unroll
      for (int i = 0; i < 4; i++)
#pragma unroll
        for (int j = 0; j < 4; j++)
          acc[i][j] = __builtin_amdgcn_mfma_f32_16x16x32_bf16(af[i], bfq[j], acc[i][j], 0, 0, 0);
    }
  }
#pragma unroll
  for (int i = 0; i < 4; i++)
#pragma unroll
    for (int j = 0; j < 4; j++) {
      int gcol = bn + wn + j * 16 + fr;
      float bvv = bias[gcol];
#pragma unroll
      for (int v = 0; v < 4; v++) {
        int grow = bm + wm + i * 16 + (lane >> 4) * 4 + v;
        float val = acc[i][j][v] + bvv;
        size_t o = (size_t)grow * Dd + gcol;
        bond[o] = val;
        bondBf[o] = f2bf(val);
      }
    }
}

// ---------------- main 256x256 MFMA GEMM, all-bf16 operands via global_load_lds ----------------
struct GP {
  const unsigned short* Wt;     // [NC][K] bf16
  const float* bias;            // [NC]
  const unsigned short* bondBf; // [ROWS][256] bf16 mirror
  const unsigned short* atomBf; // [B*N][256] bf16 mirror
  const unsigned short* h1;     // [HALF][512] bf16
  const int* conn;              // [ROWS][2]
  const float* dist;            // [ROWS]
  float* bond;                  // [ROWS][256] f32 master
  unsigned short* outH1;        // [HALF][512]
  unsigned short* outBondBf;    // mirror
  float* atomMaster;            // [B*N][256] f32 (node2 atomics)
  int rowBase;                  // 0 or HALF
};

#define A_EDGE1 0
#define A_NODE1 1
#define A_H1    2
#define EP_H1RELU 0
#define EP_EDGE2  1
#define EP_NODE2  2

template <int K, int NC, int BN, int AL, int EP>
__global__ __launch_bounds__(512, 2) void gemm256(GP p) {
  constexpr int WN = BN / 64;    // waves along N (4 or 2)
  constexpr int WM = 8 / WN;     // waves along M (2 or 4)
  constexpr int MF = 16 / WM;    // 16x16 M-frags per wave (8 or 4)
  constexpr int ABUF = 32768;            // 256 rows x 128 B
  constexpr int BBUF = BN * 128;
  constexpr int BOFF = 2 * ABUF;
  __shared__ __align__(16) char lds[2 * ABUF + 2 * BBUF];

  const int t = threadIdx.x;
  const int w = t >> 6, l = t & 63;
  constexpr int NT = NC / BN;
  const int bn = (blockIdx.x % NT) * BN;
  const int bm = (blockIdx.x / NT) * 256;

  // staging source pointers (swizzle pre-applied to the GLOBAL address; LDS dest linear)
  const char* pR0[4]; const char* pR1[4]; const char* pR2[4];
  const char* pW[WN];
#pragma unroll
  for (int i = 0; i < 4; i++) {
    int r = (w * 4 + i) * 8 + (l >> 3);      // A-tile row 0..255
    int swz = (((l & 7) ^ (r & 7)) << 4);    // pre-swizzled 16B-chunk
    if (AL == A_H1) {
      pR0[i] = (const char*)p.h1 + (size_t)(bm + r) * (K * 2) + swz;
      pR1[i] = pR0[i]; pR2[i] = pR0[i];
    } else {
      int gr = p.rowBase + bm + r;
      int b = gr / Ee;
      int i0 = p.conn[2 * gr], i1 = p.conn[2 * gr + 1];
      const char* bondRow = (const char*)p.bondBf + (size_t)gr * 512 + swz;
      const char* srcRow = (const char*)p.atomBf + ((size_t)b * Nn + i1) * 512 + swz;
      const char* tgtRow = (const char*)p.atomBf + ((size_t)b * Nn + i0) * 512 + swz;
      if (AL == A_EDGE1) { pR0[i] = bondRow; pR1[i] = srcRow; pR2[i] = tgtRow; }
      else               { pR0[i] = srcRow;  pR1[i] = bondRow; pR2[i] = bondRow; }
    }
  }
#pragma unroll
  for (int i = 0; i < WN; i++) {
    int r = (w * WN + i) * 8 + (l >> 3);     // B-tile row 0..BN-1
    int swz = (((l & 7) ^ (r & 7)) << 4);
    pW[i] = (const char*)p.Wt + (size_t)(bn + r) * (K * 2) + swz;
  }

  const int fr = l & 15;
  const int ck0 = l >> 4;
  const int wr = w / WN, wc = w % WN;
  const int wm = wr * (MF * 16);
  const int wn = wc * 64;

  f32x4 acc[MF][4] = {};

  auto stage = [&](int pb, int k0) {
#pragma unroll
    for (int i = 0; i < 4; i++) {
      const char* src;
      if (AL == A_H1)         src = pR0[i] + k0 * 2;
      else if (AL == A_EDGE1) src = (k0 < 256 ? pR0[i] : (k0 < 512 ? pR1[i] : pR2[i])) + (k0 & 255) * 2;
      else                    src = (k0 < 256 ? pR0[i] : pR1[i]) + (k0 & 255) * 2;
      gload16(src, lds + pb * ABUF + (w * 4 + i) * 1024);
    }
#pragma unroll
    for (int i = 0; i < WN; i++)
      gload16(pW[i] + k0 * 2, lds + BOFF + pb * BBUF + (w * WN + i) * 1024);
  };

  auto compute = [&](int pb) {
#pragma unroll
    for (int kk = 0; kk < 2; kk++) {
      const int ck = kk * 4 + ck0;           // logical 16B chunk within row
      bf16x8 av[MF], bv[4];
#pragma unroll
      for (int f = 0; f < MF; f++) {
        int r = wm + f * 16 + fr;
        av[f] = *(const bf16x8*)(lds + pb * ABUF + r * 128 + ((ck ^ (r & 7)) << 4));
      }
#pragma unroll
      for (int n = 0; n < 4; n++) {
        int rq = wn + n * 16 + fr;
        bv[n] = *(const bf16x8*)(lds + BOFF + pb * BBUF + rq * 128 + ((ck ^ (rq & 7)) << 4));
      }
#pragma unroll
      for (int f = 0; f < MF; f++)
#pragma unroll
        for (int n = 0; n < 4; n++)
          acc[f][n] = __builtin_amdgcn_mfma_f32_16x16x32_bf16(av[f], bv[n], acc[f][n], 0, 0, 0);
    }
  };

  constexpr int nT = K / 64;
  stage(0, 0);
  __syncthreads();               // drains vmcnt before first compute
  for (int tt = 0; tt < nT; tt++) {
    int pb = tt & 1;
    if (tt + 1 < nT) stage(pb ^ 1, (tt + 1) * 64);
    compute(pb);
    __syncthreads();             // drains next-stage vmcnt + this compute's lgkm
  }

  // ---- epilogue ----
  float bias4[4];
#pragma unroll
  for (int n = 0; n < 4; n++) bias4[n] = p.bias[bn + wn + n * 16 + fr];

#pragma unroll
  for (int f = 0; f < MF; f++) {
#pragma unroll
    for (int v = 0; v < 4; v++) {
      int lrow = bm + wm + f * 16 + (l >> 4) * 4 + v;
      if (EP == EP_H1RELU) {
#pragma unroll
        for (int n = 0; n < 4; n++) {
          int gcol = bn + wn + n * 16 + fr;
          float val = acc[f][n][v] + bias4[n];
          p.outH1[(size_t)lrow * 512 + gcol] = f2bf(fmaxf(val, 0.f));
        }
      } else if (EP == EP_EDGE2) {
        int grow = p.rowBase + lrow;
        if (p.dist[grow] != 0.f) {
#pragma unroll
          for (int n = 0; n < 4; n++) {
            int gcol = bn + wn + n * 16 + fr;
            size_t o = (size_t)grow * Dd + gcol;
            float nv = p.bond[o] + acc[f][n][v] + bias4[n];
            p.bond[o] = nv;
            p.outBondBf[o] = f2bf(nv);
          }
        }
      } else {  // EP_NODE2
        int grow = p.rowBase + lrow;
        int b = grow / Ee;
        int tg = p.conn[2 * grow];
        float* dst = p.atomMaster + ((size_t)b * Nn + tg) * Dd;
#pragma unroll
        for (int n = 0; n < 4; n++) {
          int gcol = bn + wn + n * 16 + fr;
          atomicAdd(dst + gcol, acc[f][n][v] + bias4[n]);
        }
      }
    }
  }
}

// ---------------- final readout ----------------
__global__ void pool_k(const float* __restrict__ atom, const int* __restrict__ cls,
                       const float* __restrict__ meanEmb, const float* __restrict__ oW,
                       const float* __restrict__ ob, float* __restrict__ out) {
  __shared__ float w[Dd];
  __shared__ float red[256];
  __shared__ float redc[256];
  int b = blockIdx.x, t = threadIdx.x;
  w[t] = oW[t];
  __syncthreads();
  float sum = 0.f, cnt = 0.f;
  for (int n = t; n < Nn; n += 256) {
    int site = b * Nn + n;
    int c = cls[site];
    const float* a = atom + (size_t)site * Dd;
    float dot = 0.f;
    for (int d = 0; d < Dd; d++) dot += a[d] * w[d];
    if (c != 0) { sum += meanEmb[c] + dot + ob[0]; cnt += 1.f; }
  }
  red[t] = sum; redc[t] = cnt;
  __syncthreads();
  for (int s = 128; s > 0; s >>= 1) {
    if (t < s) { red[t] += red[t + s]; redc[t] += redc[t + s]; }
    __syncthreads();
  }
  if (t == 0) out[b] = red[0] / redc[0];
}

extern "C" void kernel_launch(void* const* d_in, const int* in_sizes, int n_in,
                              void* d_out, int out_size, void* d_ws, size_t ws_size,
                              hipStream_t stream) {
  const int* site_class = (const int*)d_in[0];
  const float* distance = (const float*)d_in[1];
  const int* conn       = (const int*)d_in[2];
  const float* atom_emb = (const float*)d_in[3];
  const float* mean_emb = (const float*)d_in[4];
  const float* centers  = (const float*)d_in[5];
  const float* gapP     = (const float*)d_in[6];
  const float* bond_W   = (const float*)d_in[7];
  const float* bond_b   = (const float*)d_in[8];
  const float* offset_W = (const float*)d_in[9];
  const float* offset_b = (const float*)d_in[10];
  const float* edge_W1  = (const float*)d_in[11];
  const float* edge_b1  = (const float*)d_in[12];
  const float* edge_W2  = (const float*)d_in[13];
  const float* edge_b2  = (const float*)d_in[14];
  const float* node_W1  = (const float*)d_in[15];
  const float* node_b1  = (const float*)d_in[16];
  const float* node_W2  = (const float*)d_in[17];
  const float* node_b2  = (const float*)d_in[18];

  char* ws = (char*)d_ws;
  float* atom            = (float*)(ws + 0);                    //   8,388,608
  unsigned short* atomBf = (unsigned short*)(ws + 8388608);     //   4,194,304
  float* bond            = (float*)(ws + 12582912);             // 100,663,296
  unsigned short* bondBf = (unsigned short*)(ws + 113246208);   //  50,331,648
  unsigned short* h1     = (unsigned short*)(ws + 163577856);   //  50,331,648
  unsigned short* bWT    = (unsigned short*)(ws + 213909504);   //      65,536
  unsigned short* eW1T   = (unsigned short*)(ws + 213975040);   //   4,718,592
  unsigned short* eW2T   = (unsigned short*)(ws + 218693632);   //   1,572,864
  unsigned short* nW1T   = (unsigned short*)(ws + 220266496);   //   3,145,728
  unsigned short* nW2T   = (unsigned short*)(ws + 223412224);   //   1,572,864  (end 224,985,088)

  dim3 tb(32, 8);
  transpose_w<<<dim3(4, 8, 1), tb, 0, stream>>>(bond_W, bWT, 128, 256);
  transpose_w<<<dim3(24, 16, 6), tb, 0, stream>>>(edge_W1, eW1T, 768, 512);
  transpose_w<<<dim3(16, 8, 6), tb, 0, stream>>>(edge_W2, eW2T, 512, 256);
  transpose_w<<<dim3(16, 16, 6), tb, 0, stream>>>(node_W1, nW1T, 512, 512);
  transpose_w<<<dim3(16, 8, 6), tb, 0, stream>>>(node_W2, nW2T, 512, 256);

  atom_init<<<Bb * Nn, 256, 0, stream>>>(site_class, atom_emb, atom, atomBf);
  gemm_rbf<<<dim3(768, 2), 256, 0, stream>>>(bWT, bond_b, distance, centers, gapP, bond, bondBf);

  GP base{};
  base.conn = conn; base.dist = distance;
  base.bondBf = bondBf; base.atomBf = atomBf; base.h1 = h1;
  base.bond = bond; base.outH1 = h1; base.outBondBf = bondBf; base.atomMaster = atom;

  for (int i = 0; i < 6; i++) {
    for (int h = 0; h < 2; h++) {
      GP q = base; q.rowBase = h * HALF;
      q.Wt = eW1T + (size_t)i * 512 * 768; q.bias = edge_b1 + i * 512;
      gemm256<768, 512, 256, A_EDGE1, EP_H1RELU><<<384, 512, 0, stream>>>(q);
      GP q2 = base; q2.rowBase = h * HALF;
      q2.Wt = eW2T + (size_t)i * 256 * 512; q2.bias = edge_b2 + i * 256;
      gemm256<512, 256, 128, A_H1, EP_EDGE2><<<384, 512, 0, stream>>>(q2);
    }
    for (int h = 0; h < 2; h++) {
      GP q = base; q.rowBase = h * HALF;
      q.Wt = nW1T + (size_t)i * 512 * 512; q.bias = node_b1 + i * 512;
      gemm256<512, 512, 256, A_NODE1, EP_H1RELU><<<384, 512, 0, stream>>>(q);
      GP q2 = base; q2.rowBase = h * HALF;
      q2.Wt = nW2T + (size_t)i * 256 * 512; q2.bias = node_b2 + i * 256;
      gemm256<512, 256, 128, A_H1, EP_NODE2><<<384, 512, 0, stream>>>(q2);
    }
    atom_fix<<<Bb * Nn, 256, 0, stream>>>(site_class, atom_emb, atom, atomBf);
  }

  pool_k<<<Bb, 256, 0, stream>>>(atom, site_class, mean_emb, offset_W, offset_b, (float*)d_out);
}